// Round 3
// baseline (1151.268 us; speedup 1.0000x reference)
//
#include <hip/hip_runtime.h>
#include <math.h>

#define BATCH 1024
#define HID 256

typedef __bf16 bf16_t;
typedef __bf16 bf16x8 __attribute__((ext_vector_type(8)));
typedef float f32x4 __attribute__((ext_vector_type(4)));

struct ProjDesc {
    const float* left;   // [B][H] or nullptr (zeros)
    const float* up;     // [B][H] or nullptr (zeros)
    const float* prev;   // [B][H]
    const float* W;      // [H][3H] row-major
    const float* bias;   // [H]
    float* out;          // [B][H]
};
struct ProjBatchArgs { ProjDesc d[18]; };

struct CellDesc {
    const float* ph;     // [B][H]
    const float* pc;     // [B][H]
    const float* Whh;    // [4H][H] row-major
    const float* Wih;    // [4H]
    const float* bih;    // [4H]
    const float* bhh;    // [4H]
    const float* xcol;   // x + i*GW + j, stride 81 per batch
    float* gh;           // [B][H]
    float* gc;           // [B][H]
};
struct CellBatchArgs { CellDesc d[9]; };

__device__ inline bf16x8 cvt8(const float4 a, const float4 b) {
    bf16x8 r;
    r[0] = (bf16_t)a.x; r[1] = (bf16_t)a.y; r[2] = (bf16_t)a.z; r[3] = (bf16_t)a.w;
    r[4] = (bf16_t)b.x; r[5] = (bf16_t)b.y; r[6] = (bf16_t)b.z; r[7] = (bf16_t)b.w;
    return r;
}

// out[b][n] = sum_k comb[b][k] * W[n][k] + bias[n], comb = [left|up|prev].
// Tile: 128 batch x 128 units, BK=32, bf16 MFMA 16x16x32, fp32 accum.
// Waves 2x2, wave tile 64x64 -> 4x4 fragments (16 MFMA : 8 ds_read_b128).
// Register-staged prefetch: next K-slab loads issued before MFMA phase.
__global__ __launch_bounds__(256) void proj_kernel(ProjBatchArgs args) {
    const ProjDesc pd = args.d[blockIdx.z];
    __shared__ bf16_t Asm[128][40];
    __shared__ bf16_t Bsm[128][40];
    const int t = threadIdx.x;
    const int lane = t & 63, wid = t >> 6;
    const int wm = wid & 1, wn = wid >> 1;
    const int ln = lane & 15, lh = lane >> 4;
    const int b0 = blockIdx.x * 128;
    const int n0 = blockIdx.y * 128;
    const int sr = t >> 1, sq = (t & 1) * 16;   // staging: 128 rows x 32 k, 16 f32/thread

    const float* aSeg[3]; int kOff[3]; int nseg = 0;
    if (pd.left) { aSeg[nseg] = pd.left; kOff[nseg] = 0;   ++nseg; }
    if (pd.up)   { aSeg[nseg] = pd.up;   kOff[nseg] = 256; ++nseg; }
    aSeg[nseg] = pd.prev; kOff[nseg] = 512; ++nseg;
    const int iters = nseg * 8;

    const size_t aoff = (size_t)(b0 + sr) * HID + sq;
    const float* wbase = pd.W + (size_t)(n0 + sr) * (3 * HID) + sq;

    f32x4 acc[4][4] = {};
    float4 sa[4], sb[4];
    {
        const float* ap = aSeg[0] + aoff;
        const float* wp = wbase + kOff[0];
        #pragma unroll
        for (int m = 0; m < 4; ++m) sa[m] = *(const float4*)(ap + m * 4);
        #pragma unroll
        for (int m = 0; m < 4; ++m) sb[m] = *(const float4*)(wp + m * 4);
    }
    for (int i = 0; i < iters; ++i) {
        const bf16x8 av0 = cvt8(sa[0], sa[1]), av1 = cvt8(sa[2], sa[3]);
        const bf16x8 bv0 = cvt8(sb[0], sb[1]), bv1 = cvt8(sb[2], sb[3]);
        __syncthreads();
        *(bf16x8*)&Asm[sr][sq] = av0;
        *(bf16x8*)&Asm[sr][sq + 8] = av1;
        *(bf16x8*)&Bsm[sr][sq] = bv0;
        *(bf16x8*)&Bsm[sr][sq + 8] = bv1;
        __syncthreads();
        if (i + 1 < iters) {
            const int s = (i + 1) >> 3, kb = (i + 1) & 7;
            const float* ap = aSeg[s] + aoff + kb * 32;
            const float* wp = wbase + kOff[s] + kb * 32;
            #pragma unroll
            for (int m = 0; m < 4; ++m) sa[m] = *(const float4*)(ap + m * 4);
            #pragma unroll
            for (int m = 0; m < 4; ++m) sb[m] = *(const float4*)(wp + m * 4);
        }
        bf16x8 af[4], bfv[4];
        #pragma unroll
        for (int mf = 0; mf < 4; ++mf)
            af[mf] = *(const bf16x8*)&Asm[wm * 64 + mf * 16 + ln][lh * 8];
        #pragma unroll
        for (int nf = 0; nf < 4; ++nf)
            bfv[nf] = *(const bf16x8*)&Bsm[wn * 64 + nf * 16 + ln][lh * 8];
        #pragma unroll
        for (int mf = 0; mf < 4; ++mf)
            #pragma unroll
            for (int nf = 0; nf < 4; ++nf)
                acc[mf][nf] = __builtin_amdgcn_mfma_f32_16x16x32_bf16(
                    af[mf], bfv[nf], acc[mf][nf], 0, 0, 0);
    }
    #pragma unroll
    for (int nf = 0; nf < 4; ++nf) {
        const int n = n0 + wn * 64 + nf * 16 + ln;
        const float bias = pd.bias[n];
        #pragma unroll
        for (int mf = 0; mf < 4; ++mf)
            #pragma unroll
            for (int r = 0; r < 4; ++r) {
                const int b = b0 + wm * 64 + mf * 16 + lh * 4 + r;
                pd.out[(size_t)b * HID + n] = acc[mf][nf][r] + bias;
            }
    }
}

// gates + fused LSTM elementwise. Tile: 128 batch x (4 gates x 32 units),
// B-tile row c = g*32 + du. Wave frags pick rows g*32 + wn*16 + ln so each
// thread holds all 4 gates of its unit -> elementwise fully local.
__global__ __launch_bounds__(256) void cell_kernel(CellBatchArgs args) {
    const CellDesc cd = args.d[blockIdx.z];
    __shared__ bf16_t Psm[128][40];
    __shared__ bf16_t Wsm[128][40];
    const int t = threadIdx.x;
    const int lane = t & 63, wid = t >> 6;
    const int wm = wid & 1, wn = wid >> 1;
    const int ln = lane & 15, lh = lane >> 4;
    const int b0 = blockIdx.x * 128;
    const int u0 = blockIdx.y * 32;
    const int sr = t >> 1, sq = (t & 1) * 16;

    const float* pbase = cd.ph + (size_t)(b0 + sr) * HID + sq;
    const int cg = sr >> 5, cdu = sr & 31;
    const float* wbase = cd.Whh + (size_t)(cg * HID + u0 + cdu) * HID + sq;

    f32x4 acc[4][4] = {};
    float4 sa[4], sb[4];
    #pragma unroll
    for (int m = 0; m < 4; ++m) sa[m] = *(const float4*)(pbase + m * 4);
    #pragma unroll
    for (int m = 0; m < 4; ++m) sb[m] = *(const float4*)(wbase + m * 4);

    for (int kb = 0; kb < 8; ++kb) {
        const bf16x8 pv0 = cvt8(sa[0], sa[1]), pv1 = cvt8(sa[2], sa[3]);
        const bf16x8 wv0 = cvt8(sb[0], sb[1]), wv1 = cvt8(sb[2], sb[3]);
        __syncthreads();
        *(bf16x8*)&Psm[sr][sq] = pv0;
        *(bf16x8*)&Psm[sr][sq + 8] = pv1;
        *(bf16x8*)&Wsm[sr][sq] = wv0;
        *(bf16x8*)&Wsm[sr][sq + 8] = wv1;
        __syncthreads();
        if (kb + 1 < 8) {
            #pragma unroll
            for (int m = 0; m < 4; ++m) sa[m] = *(const float4*)(pbase + (kb + 1) * 32 + m * 4);
            #pragma unroll
            for (int m = 0; m < 4; ++m) sb[m] = *(const float4*)(wbase + (kb + 1) * 32 + m * 4);
        }
        bf16x8 af[4], bfr[4];
        #pragma unroll
        for (int mf = 0; mf < 4; ++mf)
            af[mf] = *(const bf16x8*)&Psm[wm * 64 + mf * 16 + ln][lh * 8];
        #pragma unroll
        for (int g = 0; g < 4; ++g)
            bfr[g] = *(const bf16x8*)&Wsm[g * 32 + wn * 16 + ln][lh * 8];
        #pragma unroll
        for (int mf = 0; mf < 4; ++mf)
            #pragma unroll
            for (int g = 0; g < 4; ++g)
                acc[mf][g] = __builtin_amdgcn_mfma_f32_16x16x32_bf16(
                    af[mf], bfr[g], acc[mf][g], 0, 0, 0);
    }

    const int u = u0 + wn * 16 + ln;
    float wih[4], bsum[4];
    #pragma unroll
    for (int g = 0; g < 4; ++g) {
        const int n = g * HID + u;
        wih[g] = cd.Wih[n];
        bsum[g] = cd.bih[n] + cd.bhh[n];
    }
    #pragma unroll
    for (int mf = 0; mf < 4; ++mf)
        #pragma unroll
        for (int r = 0; r < 4; ++r) {
            const int b = b0 + wm * 64 + mf * 16 + lh * 4 + r;
            const float xv = cd.xcol[(size_t)b * 81];
            const float gi = acc[mf][0][r] + xv * wih[0] + bsum[0];
            const float gf = acc[mf][1][r] + xv * wih[1] + bsum[1];
            const float gg = acc[mf][2][r] + xv * wih[2] + bsum[2];
            const float go = acc[mf][3][r] + xv * wih[3] + bsum[3];
            const float i_ = 1.f / (1.f + expf(-gi));
            const float f_ = 1.f / (1.f + expf(-gf));
            const float o_ = 1.f / (1.f + expf(-go));
            const float g_ = tanhf(gg);
            const float c0 = cd.pc[(size_t)b * HID + u];
            const float cn = f_ * c0 + i_ * g_;
            const float hn = o_ * tanhf(cn);
            cd.gh[(size_t)b * HID + u] = hn;
            cd.gc[(size_t)b * HID + u] = cn;
        }
}

__global__ __launch_bounds__(256) void final_kernel(
        const float* __restrict__ gh88, const float* __restrict__ gc88,
        const float* __restrict__ Wout, const float* __restrict__ bout,
        float* __restrict__ out, float* __restrict__ fh, float* __restrict__ fc) {
    const int tid = blockIdx.x * blockDim.x + threadIdx.x;
    const int nth = gridDim.x * blockDim.x;
    for (int idx = tid; idx < BATCH * HID; idx += nth) {
        fh[idx] = gh88[idx];
        fc[idx] = gc88[idx];
    }
    if (tid < BATCH) {
        float s = bout[0];
        for (int k = 0; k < HID; ++k) s += gh88[(size_t)tid * HID + k] * Wout[k];
        s = fmaxf(s, 0.f);
        out[tid] = 1.f / (1.f + expf(-s));
    }
}

extern "C" void kernel_launch(void* const* d_in, const int* in_sizes, int n_in,
                              void* d_out, int out_size, void* d_ws, size_t ws_size,
                              hipStream_t stream) {
    const float* x      = (const float*)d_in[0];
    const float* h_ext  = (const float*)d_in[1];
    const float* c_ext  = (const float*)d_in[2];
    const float* grid_h = (const float*)d_in[3];
    const float* grid_c = (const float*)d_in[4];
    const float* W_hp   = (const float*)d_in[5];
    const float* b_hp   = (const float*)d_in[6];
    const float* W_cp   = (const float*)d_in[7];
    const float* b_cp   = (const float*)d_in[8];
    const float* W_ih   = (const float*)d_in[9];
    const float* W_hh   = (const float*)d_in[10];
    const float* b_ih   = (const float*)d_in[11];
    const float* b_hh   = (const float*)d_in[12];
    const float* W_out  = (const float*)d_in[13];
    const float* b_out  = (const float*)d_in[14];

    float* out = (float*)d_out;
    float* fh  = out + BATCH * 1;
    float* fc  = fh + BATCH * HID;
    float* gh  = fc + BATCH * HID;
    float* gc  = gh + (size_t)81 * BATCH * HID;

    float* ws = (float*)d_ws;   // 18 * B * H floats = 18 MB

    for (int d = 0; d <= 16; ++d) {
        const int i_lo = d > 8 ? d - 8 : 0;
        const int i_hi = d < 8 ? d : 8;
        const int nc = i_hi - i_lo + 1;
        ProjBatchArgs pa{};
        CellBatchArgs ca{};
        for (int s = 0; s < nc; ++s) {
            const int i = i_lo + s, j = d - i;
            const int k = i * 9 + j;
            const float *hl, *cl, *hu, *cu;
            if (i == 0 && j == 0)      { hl = h_ext; cl = c_ext; }
            else if (j > 0)            { hl = gh + (size_t)(k - 1) * BATCH * HID;
                                         cl = gc + (size_t)(k - 1) * BATCH * HID; }
            else                       { hl = nullptr; cl = nullptr; }
            if (i > 0)                 { hu = gh + (size_t)(k - 9) * BATCH * HID;
                                         cu = gc + (size_t)(k - 9) * BATCH * HID; }
            else                       { hu = nullptr; cu = nullptr; }
            const float* hp = grid_h + (size_t)k * BATCH * HID;
            const float* cp = grid_c + (size_t)k * BATCH * HID;
            float* ph = ws + (size_t)s * 2 * BATCH * HID;
            float* pc = ph + BATCH * HID;
            pa.d[2 * s + 0] = { hl, hu, hp, W_hp + (size_t)k * HID * 3 * HID,
                                b_hp + (size_t)k * HID, ph };
            pa.d[2 * s + 1] = { cl, cu, cp, W_cp + (size_t)k * HID * 3 * HID,
                                b_cp + (size_t)k * HID, pc };
            ca.d[s] = { ph, pc,
                        W_hh + (size_t)k * 4 * HID * HID,
                        W_ih + (size_t)k * 4 * HID,
                        b_ih + (size_t)k * 4 * HID,
                        b_hh + (size_t)k * 4 * HID,
                        x + i * 9 + j,
                        gh + (size_t)k * BATCH * HID,
                        gc + (size_t)k * BATCH * HID };
        }
        proj_kernel<<<dim3(8, 2, 2 * nc), 256, 0, stream>>>(pa);
        cell_kernel<<<dim3(8, 8, nc), 256, 0, stream>>>(ca);
    }
    final_kernel<<<dim3(64), 256, 0, stream>>>(
        gh + (size_t)80 * BATCH * HID, gc + (size_t)80 * BATCH * HID,
        W_out, b_out, out, fh, fc);
}

// Round 4
// 1094.535 us; speedup vs baseline: 1.0518x; 1.0518x over previous
//
#include <hip/hip_runtime.h>
#include <math.h>

#define BATCH 1024
#define HID 256
#define W3 768
#define SLOT (BATCH * HID)

typedef __bf16 bf16_t;
typedef __bf16 bf16x8 __attribute__((ext_vector_type(8)));
typedef float f32x4 __attribute__((ext_vector_type(4)));

__device__ inline bf16x8 cvt8(const float4 a, const float4 b) {
    bf16x8 r;
    r[0] = (bf16_t)a.x; r[1] = (bf16_t)a.y; r[2] = (bf16_t)a.z; r[3] = (bf16_t)a.w;
    r[4] = (bf16_t)b.x; r[5] = (bf16_t)b.y; r[6] = (bf16_t)b.z; r[7] = (bf16_t)b.w;
    return r;
}

// One 128x128 output tile of  out[b][n] (+)= sum_k src[b][k] * W[n][koff+k],
// K=256, W rows are 768 wide. ATOMIC: atomic-add into out (no bias).
// Non-atomic: overwrite with + bias[n].
template<bool ATOMIC>
__device__ __forceinline__ void proj_core(
        const float* __restrict__ src, const float* __restrict__ W, int koff,
        const float* __restrict__ bias, float* __restrict__ out,
        bf16_t (*Asm)[40], bf16_t (*Bsm)[40]) {
    const int t = threadIdx.x;
    const int lane = t & 63, wid = t >> 6;
    const int wm = wid & 1, wn = wid >> 1;
    const int ln = lane & 15, lh = lane >> 4;
    const int b0 = blockIdx.x * 128, n0 = blockIdx.y * 128;
    const int sr = t >> 1, sq = (t & 1) * 16;
    const float* arow = src + (size_t)(b0 + sr) * HID + sq;
    const float* wrow = W + (size_t)(n0 + sr) * W3 + koff + sq;
    f32x4 acc[4][4] = {};
    for (int kb = 0; kb < 8; ++kb) {
        const float4 a0 = *(const float4*)(arow + kb * 32);
        const float4 a1 = *(const float4*)(arow + kb * 32 + 4);
        const float4 a2 = *(const float4*)(arow + kb * 32 + 8);
        const float4 a3 = *(const float4*)(arow + kb * 32 + 12);
        const float4 w0 = *(const float4*)(wrow + kb * 32);
        const float4 w1 = *(const float4*)(wrow + kb * 32 + 4);
        const float4 w2 = *(const float4*)(wrow + kb * 32 + 8);
        const float4 w3 = *(const float4*)(wrow + kb * 32 + 12);
        const bf16x8 av0 = cvt8(a0, a1), av1 = cvt8(a2, a3);
        const bf16x8 bv0 = cvt8(w0, w1), bv1 = cvt8(w2, w3);
        __syncthreads();
        *(bf16x8*)&Asm[sr][sq] = av0;
        *(bf16x8*)&Asm[sr][sq + 8] = av1;
        *(bf16x8*)&Bsm[sr][sq] = bv0;
        *(bf16x8*)&Bsm[sr][sq + 8] = bv1;
        __syncthreads();
        bf16x8 af[4], bfv[4];
        #pragma unroll
        for (int mf = 0; mf < 4; ++mf)
            af[mf] = *(const bf16x8*)&Asm[wm * 64 + mf * 16 + ln][lh * 8];
        #pragma unroll
        for (int nf = 0; nf < 4; ++nf)
            bfv[nf] = *(const bf16x8*)&Bsm[wn * 64 + nf * 16 + ln][lh * 8];
        #pragma unroll
        for (int mf = 0; mf < 4; ++mf)
            #pragma unroll
            for (int nf = 0; nf < 4; ++nf)
                acc[mf][nf] = __builtin_amdgcn_mfma_f32_16x16x32_bf16(
                    af[mf], bfv[nf], acc[mf][nf], 0, 0, 0);
    }
    #pragma unroll
    for (int nf = 0; nf < 4; ++nf) {
        const int n = n0 + wn * 64 + nf * 16 + ln;
        const float bn = ATOMIC ? 0.f : bias[n];
        #pragma unroll
        for (int mf = 0; mf < 4; ++mf)
            #pragma unroll
            for (int r = 0; r < 4; ++r) {
                const int b = b0 + wm * 64 + mf * 16 + lh * 4 + r;
                if (ATOMIC)
                    unsafeAtomicAdd(out + (size_t)b * HID + n, acc[mf][nf][r]);
                else
                    out[(size_t)b * HID + n] = acc[mf][nf][r] + bn;
            }
    }
}

// Upfront, fully parallel: base[z] = grid_{h,c}[k] @ Wprev.T + bias for all
// 81 cells x {h,c}.  z = 2k + hc.
__global__ __launch_bounds__(256) void prevproj_kernel(
        const float* __restrict__ gridh, const float* __restrict__ gridc,
        const float* __restrict__ Whp, const float* __restrict__ Wcp,
        const float* __restrict__ bhp, const float* __restrict__ bcp,
        float* __restrict__ pall) {
    __shared__ bf16_t As[128][40];
    __shared__ bf16_t Bs[128][40];
    const int z = blockIdx.z, k = z >> 1, hc = z & 1;
    const float* src = (hc ? gridc : gridh) + (size_t)k * SLOT;
    const float* W = (hc ? Wcp : Whp) + (size_t)k * HID * W3;
    const float* bias = (hc ? bcp : bhp) + (size_t)k * HID;
    proj_core<false>(src, W, 512, bias, pall + (size_t)z * SLOT, As, Bs);
}

struct SegDesc { const float* src; const float* W; const float* bias; float* out; int koff; };
struct SegArgs { SegDesc d[36]; };

__global__ __launch_bounds__(256) void projseg_kernel(SegArgs a) {
    __shared__ bf16_t As[128][40];
    __shared__ bf16_t Bs[128][40];
    const SegDesc d = a.d[blockIdx.z];
    if (d.bias) proj_core<false>(d.src, d.W, d.koff, d.bias, d.out, As, Bs);
    else        proj_core<true>(d.src, d.W, d.koff, nullptr, d.out, As, Bs);
}

struct CellDesc {
    const float* ph; const float* pc;
    const float* Whh; const float* Wih; const float* bih; const float* bhh;
    const float* xcol;
    float* gh; float* gc;
};
struct CellBatchArgs { CellDesc d[9]; };

// gates + fused LSTM elementwise. 128 batch x (4 gates x 32 units) tile;
// frag nf == gate so each thread holds all 4 gates of its unit.
__global__ __launch_bounds__(256) void cell_kernel(CellBatchArgs args) {
    const CellDesc cd = args.d[blockIdx.z];
    __shared__ bf16_t Psm[128][40];
    __shared__ bf16_t Wsm[128][40];
    const int t = threadIdx.x;
    const int lane = t & 63, wid = t >> 6;
    const int wm = wid & 1, wn = wid >> 1;
    const int ln = lane & 15, lh = lane >> 4;
    const int b0 = blockIdx.x * 128;
    const int u0 = blockIdx.y * 32;
    const int sr = t >> 1, sq = (t & 1) * 16;
    const float* prow = cd.ph + (size_t)(b0 + sr) * HID + sq;
    const int cg = sr >> 5, cdu = sr & 31;
    const float* wrow = cd.Whh + (size_t)(cg * HID + u0 + cdu) * HID + sq;

    f32x4 acc[4][4] = {};
    for (int kb = 0; kb < 8; ++kb) {
        const float4 p0 = *(const float4*)(prow + kb * 32);
        const float4 p1 = *(const float4*)(prow + kb * 32 + 4);
        const float4 p2 = *(const float4*)(prow + kb * 32 + 8);
        const float4 p3 = *(const float4*)(prow + kb * 32 + 12);
        const float4 w0 = *(const float4*)(wrow + kb * 32);
        const float4 w1 = *(const float4*)(wrow + kb * 32 + 4);
        const float4 w2 = *(const float4*)(wrow + kb * 32 + 8);
        const float4 w3 = *(const float4*)(wrow + kb * 32 + 12);
        const bf16x8 pv0 = cvt8(p0, p1), pv1 = cvt8(p2, p3);
        const bf16x8 wv0 = cvt8(w0, w1), wv1 = cvt8(w2, w3);
        __syncthreads();
        *(bf16x8*)&Psm[sr][sq] = pv0;
        *(bf16x8*)&Psm[sr][sq + 8] = pv1;
        *(bf16x8*)&Wsm[sr][sq] = wv0;
        *(bf16x8*)&Wsm[sr][sq + 8] = wv1;
        __syncthreads();
        bf16x8 af[4], bfr[4];
        #pragma unroll
        for (int mf = 0; mf < 4; ++mf)
            af[mf] = *(const bf16x8*)&Psm[wm * 64 + mf * 16 + ln][lh * 8];
        #pragma unroll
        for (int g = 0; g < 4; ++g)
            bfr[g] = *(const bf16x8*)&Wsm[g * 32 + wn * 16 + ln][lh * 8];
        #pragma unroll
        for (int mf = 0; mf < 4; ++mf)
            #pragma unroll
            for (int g = 0; g < 4; ++g)
                acc[mf][g] = __builtin_amdgcn_mfma_f32_16x16x32_bf16(
                    af[mf], bfr[g], acc[mf][g], 0, 0, 0);
    }

    const int u = u0 + wn * 16 + ln;
    float wih[4], bsum[4];
    #pragma unroll
    for (int g = 0; g < 4; ++g) {
        const int n = g * HID + u;
        wih[g] = cd.Wih[n];
        bsum[g] = cd.bih[n] + cd.bhh[n];
    }
    #pragma unroll
    for (int mf = 0; mf < 4; ++mf)
        #pragma unroll
        for (int r = 0; r < 4; ++r) {
            const int b = b0 + wm * 64 + mf * 16 + lh * 4 + r;
            const float xv = cd.xcol[(size_t)b * 81];
            const float gi = acc[mf][0][r] + xv * wih[0] + bsum[0];
            const float gf = acc[mf][1][r] + xv * wih[1] + bsum[1];
            const float gg = acc[mf][2][r] + xv * wih[2] + bsum[2];
            const float go = acc[mf][3][r] + xv * wih[3] + bsum[3];
            const float i_ = 1.f / (1.f + expf(-gi));
            const float f_ = 1.f / (1.f + expf(-gf));
            const float o_ = 1.f / (1.f + expf(-go));
            const float g_ = tanhf(gg);
            const float c0 = cd.pc[(size_t)b * HID + u];
            const float cn = f_ * c0 + i_ * g_;
            const float hn = o_ * tanhf(cn);
            cd.gh[(size_t)b * HID + u] = hn;
            cd.gc[(size_t)b * HID + u] = cn;
        }
}

__global__ __launch_bounds__(256) void final_kernel(
        const float* __restrict__ gh88, const float* __restrict__ gc88,
        const float* __restrict__ Wout, const float* __restrict__ bout,
        float* __restrict__ out, float* __restrict__ fh, float* __restrict__ fc) {
    const int tid = blockIdx.x * blockDim.x + threadIdx.x;
    const int nth = gridDim.x * blockDim.x;
    for (int idx = tid; idx < BATCH * HID; idx += nth) {
        fh[idx] = gh88[idx];
        fc[idx] = gc88[idx];
    }
    if (tid < BATCH) {
        float s = bout[0];
        for (int k = 0; k < HID; ++k) s += gh88[(size_t)tid * HID + k] * Wout[k];
        s = fmaxf(s, 0.f);
        out[tid] = 1.f / (1.f + expf(-s));
    }
}

extern "C" void kernel_launch(void* const* d_in, const int* in_sizes, int n_in,
                              void* d_out, int out_size, void* d_ws, size_t ws_size,
                              hipStream_t stream) {
    const float* x      = (const float*)d_in[0];
    const float* h_ext  = (const float*)d_in[1];
    const float* c_ext  = (const float*)d_in[2];
    const float* grid_h = (const float*)d_in[3];
    const float* grid_c = (const float*)d_in[4];
    const float* W_hp   = (const float*)d_in[5];
    const float* b_hp   = (const float*)d_in[6];
    const float* W_cp   = (const float*)d_in[7];
    const float* b_cp   = (const float*)d_in[8];
    const float* W_ih   = (const float*)d_in[9];
    const float* W_hh   = (const float*)d_in[10];
    const float* b_ih   = (const float*)d_in[11];
    const float* b_hh   = (const float*)d_in[12];
    const float* W_out  = (const float*)d_in[13];
    const float* b_out  = (const float*)d_in[14];

    float* out = (float*)d_out;
    float* fh  = out + BATCH * 1;
    float* fc  = fh + SLOT;
    float* gh  = fc + SLOT;
    float* gc  = gh + (size_t)81 * SLOT;

    float* ws = (float*)d_ws;
    const bool bigws = ws_size >= (size_t)162 * SLOT * 4;  // 170 MB

    if (bigws) {
        // Phase 0: all prev-projections (+bias) in parallel, off critical path.
        prevproj_kernel<<<dim3(8, 2, 162), 256, 0, stream>>>(
            grid_h, grid_c, W_hp, W_cp, b_hp, b_cp, ws);
        for (int d = 0; d <= 16; ++d) {
            const int i_lo = d > 8 ? d - 8 : 0;
            const int i_hi = d < 8 ? d : 8;
            const int nc = i_hi - i_lo + 1;
            SegArgs sa{};
            CellBatchArgs ca{};
            int nd = 0;
            for (int s = 0; s < nc; ++s) {
                const int i = i_lo + s, j = d - i;
                const int k = i * 9 + j;
                float* oh = ws + (size_t)(2 * k) * SLOT;
                float* oc = oh + SLOT;
                const float* Wh = W_hp + (size_t)k * HID * W3;
                const float* Wc = W_cp + (size_t)k * HID * W3;
                if (i == 0 && j == 0) {
                    sa.d[nd++] = { h_ext, Wh, nullptr, oh, 0 };
                    sa.d[nd++] = { c_ext, Wc, nullptr, oc, 0 };
                } else if (j > 0) {
                    sa.d[nd++] = { gh + (size_t)(k - 1) * SLOT, Wh, nullptr, oh, 0 };
                    sa.d[nd++] = { gc + (size_t)(k - 1) * SLOT, Wc, nullptr, oc, 0 };
                }
                if (i > 0) {
                    sa.d[nd++] = { gh + (size_t)(k - 9) * SLOT, Wh, nullptr, oh, 256 };
                    sa.d[nd++] = { gc + (size_t)(k - 9) * SLOT, Wc, nullptr, oc, 256 };
                }
                ca.d[s] = { oh, oc,
                            W_hh + (size_t)k * 4 * HID * HID,
                            W_ih + (size_t)k * 4 * HID,
                            b_ih + (size_t)k * 4 * HID,
                            b_hh + (size_t)k * 4 * HID,
                            x + i * 9 + j,
                            gh + (size_t)k * SLOT,
                            gc + (size_t)k * SLOT };
            }
            projseg_kernel<<<dim3(8, 2, nd), 256, 0, stream>>>(sa);
            cell_kernel<<<dim3(8, 8, nc), 256, 0, stream>>>(ca);
        }
    } else {
        // Fallback: per-diagonal base pass (store) + increment pass (atomic),
        // using 18 rotating slots in ws (18.9 MB).
        for (int d = 0; d <= 16; ++d) {
            const int i_lo = d > 8 ? d - 8 : 0;
            const int i_hi = d < 8 ? d : 8;
            const int nc = i_hi - i_lo + 1;
            SegArgs base{}, inc{};
            CellBatchArgs ca{};
            int nb = 0, ni = 0;
            for (int s = 0; s < nc; ++s) {
                const int i = i_lo + s, j = d - i;
                const int k = i * 9 + j;
                float* oh = ws + (size_t)(2 * s) * SLOT;
                float* oc = oh + SLOT;
                const float* Wh = W_hp + (size_t)k * HID * W3;
                const float* Wc = W_cp + (size_t)k * HID * W3;
                base.d[nb++] = { grid_h + (size_t)k * SLOT, Wh, b_hp + (size_t)k * HID, oh, 512 };
                base.d[nb++] = { grid_c + (size_t)k * SLOT, Wc, b_cp + (size_t)k * HID, oc, 512 };
                if (i == 0 && j == 0) {
                    inc.d[ni++] = { h_ext, Wh, nullptr, oh, 0 };
                    inc.d[ni++] = { c_ext, Wc, nullptr, oc, 0 };
                } else if (j > 0) {
                    inc.d[ni++] = { gh + (size_t)(k - 1) * SLOT, Wh, nullptr, oh, 0 };
                    inc.d[ni++] = { gc + (size_t)(k - 1) * SLOT, Wc, nullptr, oc, 0 };
                }
                if (i > 0) {
                    inc.d[ni++] = { gh + (size_t)(k - 9) * SLOT, Wh, nullptr, oh, 256 };
                    inc.d[ni++] = { gc + (size_t)(k - 9) * SLOT, Wc, nullptr, oc, 256 };
                }
                ca.d[s] = { oh, oc,
                            W_hh + (size_t)k * 4 * HID * HID,
                            W_ih + (size_t)k * 4 * HID,
                            b_ih + (size_t)k * 4 * HID,
                            b_hh + (size_t)k * 4 * HID,
                            x + i * 9 + j,
                            gh + (size_t)k * SLOT,
                            gc + (size_t)k * SLOT };
            }
            projseg_kernel<<<dim3(8, 2, nb), 256, 0, stream>>>(base);
            projseg_kernel<<<dim3(8, 2, ni), 256, 0, stream>>>(inc);
            cell_kernel<<<dim3(8, 8, nc), 256, 0, stream>>>(ca);
        }
    }
    final_kernel<<<dim3(64), 256, 0, stream>>>(
        gh + (size_t)80 * SLOT, gc + (size_t)80 * SLOT,
        W_out, b_out, out, fh, fc);
}